// Round 2
// baseline (299.929 us; speedup 1.0000x reference)
//
#include <hip/hip_runtime.h>

#define TOK 65536
#define DM 256
#define DF 1024
#define NB 4

typedef unsigned short ushort_t;
typedef unsigned int uint32;

typedef __attribute__((ext_vector_type(8))) short bf16x8;
typedef __attribute__((ext_vector_type(4))) float f32x4;

__device__ inline ushort_t f2bf(float f) {
  union { float f; unsigned int u; } v; v.f = f;
  unsigned int u = v.u;
  unsigned int r = (u + 0x7FFFu + ((u >> 16) & 1u)) >> 16;
  return (ushort_t)r;
}
__device__ inline uint32 pack2(float a, float b) {
  return (uint32)f2bf(a) | ((uint32)f2bf(b) << 16);
}

// ---------------- kernel 0: zero the per-branch counters (ws is poisoned) ---
__global__ void zero_counts_kernel(int* __restrict__ counts) {
  if (threadIdx.x < NB) counts[threadIdx.x] = 0;
}

// ---------------- kernel 0b: convert w1/w2 fp32 -> bf16 into workspace ------
// grid (1024, 2) x 256 threads; 4 floats per thread.
__global__ __launch_bounds__(256) void prep_weights_kernel(
    const float* __restrict__ w1, const float* __restrict__ w2,
    ushort_t* __restrict__ w1b, ushort_t* __restrict__ w2b)
{
  const int idx = blockIdx.x * 256 + threadIdx.x;   // float4 index
  const float* src = blockIdx.y ? w2 : w1;
  ushort_t* dst = blockIdx.y ? w2b : w1b;
  float4 v = ((const float4*)src)[idx];
  uint2 p;
  p.x = pack2(v.x, v.y);
  p.y = pack2(v.z, v.w);
  *(uint2*)(dst + (size_t)idx * 4) = p;
}

// ---------------- kernel 1: route tokens to per-branch lists + zero-fill ----
// 256 blocks x 256 threads; each block owns 256 consecutive tokens.
__global__ __launch_bounds__(256) void route_kernel(
    const int* __restrict__ b_seq, int* __restrict__ counts,
    ushort_t* __restrict__ lists, uint32* __restrict__ out32)
{
  __shared__ int s_lpos[NB];
  __shared__ int s_lbase[NB];
  __shared__ int s_b[256];
  const int tid = threadIdx.x;
  const int base = blockIdx.x * 256;
  const int token = base + tid;
  if (tid < NB) s_lpos[tid] = 0;
  __syncthreads();
  const int b = b_seq[token];
  s_b[tid] = b;
  int my = 0;
  if (b > 0) my = atomicAdd(&s_lpos[b - 1], 1);
  __syncthreads();
  if (tid < NB) s_lbase[tid] = atomicAdd(&counts[tid], s_lpos[tid]);
  __syncthreads();
  if (b > 0) lists[(b - 1) * TOK + s_lbase[b - 1] + my] = (ushort_t)token;
  // zero-fill rows of inactive tokens (b==0): 256 fp32 dwords per row
  #pragma unroll 4
  for (int it = 0; it < 256; ++it) {
    int flat = it * 256 + tid;           // 0..65535
    int tl = flat >> 8;                  // local token 0..255
    int j = flat & 255;                  // dword within row
    if (s_b[tl] == 0) out32[(size_t)(base + tl) * DM + j] = 0u;
  }
}

// ---------------- kernel 2: fused FFN + LN over gathered token tiles --------
// grid = (1024 tile slots, 4 branches), block = 256 (4 waves).
// Tile: M=64 tokens. Loop D_FF in 16 chunks of F=64.
__global__ __launch_bounds__(256, 2) void ffn_kernel(
    const float* __restrict__ x,
    const ushort_t* __restrict__ w1b_all, const float* __restrict__ b1,
    const ushort_t* __restrict__ w2b_all, const float* __restrict__ b2,
    const float* __restrict__ gamma, const float* __restrict__ beta,
    const int* __restrict__ counts, const ushort_t* __restrict__ lists,
    float* __restrict__ out)
{
  const int n = blockIdx.y;
  const int cnt = counts[n];
  const int tile0 = blockIdx.x * 64;
  if (tile0 >= cnt) return;
  const int mvalid = min(64, cnt - tile0);

  __shared__ int s_idx[64];
  __shared__ __align__(16) ushort_t sX[64][264];  // 256 + 8 pad
  __shared__ __align__(16) ushort_t sH[64][72];   // 64 + 8 pad
  __shared__ float s_ps[4][64];
  __shared__ float s_pq[4][64];
  __shared__ float s_mu[64];
  __shared__ float s_rs[64];

  const int tid  = threadIdx.x;
  const int wave = tid >> 6;
  const int lane = tid & 63;
  const int q    = lane >> 4;   // quad 0..3
  const int lc   = lane & 15;   // intra-tile row/col index

  if (tid < 64) {
    int i = tile0 + tid;
    s_idx[tid] = (int)lists[n * TOK + (i < cnt ? i : tile0)];
  }
  __syncthreads();

  // stage X tile: 64 rows x 256 fp32 -> bf16 in LDS. 4096 float4 chunks.
  #pragma unroll
  for (int it = 0; it < 16; ++it) {
    int chunk = it * 256 + tid;
    int r = chunk >> 6;
    int c = (chunk & 63) << 2;
    float4 v = *(const float4*)(x + (size_t)s_idx[r] * DM + c);
    uint2 p;
    p.x = pack2(v.x, v.y);
    p.y = pack2(v.z, v.w);
    *(uint2*)(&sX[r][c]) = p;
  }
  __syncthreads();

  f32x4 yacc[4][4];
  #pragma unroll
  for (int mi = 0; mi < 4; ++mi)
    #pragma unroll
    for (int di = 0; di < 4; ++di)
      yacc[mi][di] = (f32x4){0.f, 0.f, 0.f, 0.f};

  const ushort_t* w1b = w1b_all + (size_t)n * DF * DM;
  const ushort_t* w2b = w2b_all + (size_t)n * DM * DF;

  for (int fc = 0; fc < 16; ++fc) {
    const int f0 = fc * 64;
    const int fcol = f0 + wave * 16 + lc;   // this wave's H column (B-operand n)
    // ---- GEMM1: H[64 x 64] over K=256; wave computes column strip wave*16..+15
    f32x4 hacc[4];
    #pragma unroll
    for (int mi = 0; mi < 4; ++mi) hacc[mi] = (f32x4){0.f, 0.f, 0.f, 0.f};
    const ushort_t* w1row = w1b + (size_t)fcol * DM;
    #pragma unroll
    for (int ks = 0; ks < 8; ++ks) {
      bf16x8 bfrag = *(const bf16x8*)(w1row + ks * 32 + q * 8);
      #pragma unroll
      for (int mi = 0; mi < 4; ++mi) {
        bf16x8 afrag = *(const bf16x8*)(&sX[mi * 16 + lc][ks * 32 + q * 8]);
        hacc[mi] = __builtin_amdgcn_mfma_f32_16x16x32_bf16(afrag, bfrag, hacc[mi], 0, 0, 0);
      }
    }
    const float b1v = b1[n * DF + fcol];
    __syncthreads();   // prior chunk's GEMM2 reads of sH complete
    // ---- ELU + bias, C-layout -> row-major bf16 in LDS (A-operand for GEMM2)
    #pragma unroll
    for (int mi = 0; mi < 4; ++mi) {
      #pragma unroll
      for (int r = 0; r < 4; ++r) {
        float v = hacc[mi][r] + b1v;
        v = (v > 0.f) ? v : (__expf(v) - 1.f);
        sH[mi * 16 + q * 4 + r][wave * 16 + lc] = f2bf(v);
      }
    }
    __syncthreads();
    // ---- GEMM2: Y[64 x 256] += H @ W2^T; wave owns columns wave*64..+63
    #pragma unroll
    for (int ks = 0; ks < 2; ++ks) {
      bf16x8 af[4];
      #pragma unroll
      for (int mi = 0; mi < 4; ++mi)
        af[mi] = *(const bf16x8*)(&sH[mi * 16 + lc][ks * 32 + q * 8]);
      #pragma unroll
      for (int di = 0; di < 4; ++di) {
        const int dcol = wave * 64 + di * 16 + lc;
        bf16x8 bfrag = *(const bf16x8*)(w2b + (size_t)dcol * DF + f0 + ks * 32 + q * 8);
        #pragma unroll
        for (int mi = 0; mi < 4; ++mi)
          yacc[mi][di] = __builtin_amdgcn_mfma_f32_16x16x32_bf16(af[mi], bfrag, yacc[mi][di], 0, 0, 0);
      }
    }
  }

  // ---- epilogue: +b2, LayerNorm stats (cross-wave), gamma/beta, scatter out
  float b2v[4], gv[4], bv[4];
  #pragma unroll
  for (int di = 0; di < 4; ++di) {
    int dcol = wave * 64 + di * 16 + lc;
    b2v[di] = b2[n * DM + dcol];
    gv[di]  = gamma[n * DM + dcol];
    bv[di]  = beta[n * DM + dcol];
  }
  #pragma unroll
  for (int mi = 0; mi < 4; ++mi)
    #pragma unroll
    for (int di = 0; di < 4; ++di)
      #pragma unroll
      for (int r = 0; r < 4; ++r)
        yacc[mi][di][r] += b2v[di];

  #pragma unroll
  for (int mi = 0; mi < 4; ++mi) {
    #pragma unroll
    for (int r = 0; r < 4; ++r) {
      float s = 0.f, sq = 0.f;
      #pragma unroll
      for (int di = 0; di < 4; ++di) {
        float v = yacc[mi][di][r];
        s += v; sq += v * v;
      }
      #pragma unroll
      for (int off = 1; off < 16; off <<= 1) {
        s  += __shfl_xor(s, off, 64);
        sq += __shfl_xor(sq, off, 64);
      }
      if (lc == 0) {
        int m = mi * 16 + q * 4 + r;
        s_ps[wave][m] = s;
        s_pq[wave][m] = sq;
      }
    }
  }
  __syncthreads();
  if (tid < 64) {
    float s  = s_ps[0][tid] + s_ps[1][tid] + s_ps[2][tid] + s_ps[3][tid];
    float sq = s_pq[0][tid] + s_pq[1][tid] + s_pq[2][tid] + s_pq[3][tid];
    float mu = s * (1.f / 256.f);
    float var = fmaxf(sq * (1.f / 256.f) - mu * mu, 0.f);
    s_mu[tid] = mu;
    s_rs[tid] = rsqrtf(var + 1e-12f);
  }
  __syncthreads();

  #pragma unroll
  for (int mi = 0; mi < 4; ++mi) {
    #pragma unroll
    for (int r = 0; r < 4; ++r) {
      int m = mi * 16 + q * 4 + r;
      if (m < mvalid) {
        float mu = s_mu[m], rs = s_rs[m];
        size_t rowbase = (size_t)s_idx[m] * DM;
        #pragma unroll
        for (int di = 0; di < 4; ++di) {
          int dcol = wave * 64 + di * 16 + lc;
          float v = (yacc[mi][di][r] - mu) * rs * gv[di] + bv[di];
          out[rowbase + dcol] = v;
        }
      }
    }
  }
}

extern "C" void kernel_launch(void* const* d_in, const int* in_sizes, int n_in,
                              void* d_out, int out_size, void* d_ws, size_t ws_size,
                              hipStream_t stream) {
  const float* x     = (const float*)d_in[0];
  const int*   b_seq = (const int*)d_in[1];
  const float* w1    = (const float*)d_in[2];
  const float* b1    = (const float*)d_in[3];
  const float* w2    = (const float*)d_in[4];
  const float* b2    = (const float*)d_in[5];
  const float* gamma = (const float*)d_in[6];
  const float* beta  = (const float*)d_in[7];
  float* out = (float*)d_out;

  int* counts = (int*)d_ws;
  ushort_t* lists = (ushort_t*)((char*)d_ws + 256);                 // 512 KB
  ushort_t* w1b = (ushort_t*)((char*)d_ws + 256 + 512 * 1024);      // 2 MB
  ushort_t* w2b = w1b + (size_t)NB * DF * DM;                       // 2 MB

  hipLaunchKernelGGL(zero_counts_kernel, dim3(1), dim3(64), 0, stream, counts);
  hipLaunchKernelGGL(prep_weights_kernel, dim3(1024, 2), dim3(256), 0, stream,
                     w1, w2, w1b, w2b);
  hipLaunchKernelGGL(route_kernel, dim3(TOK / 256), dim3(256), 0, stream,
                     b_seq, counts, lists, (uint32*)d_out);
  hipLaunchKernelGGL(ffn_kernel, dim3(TOK / 64, NB), dim3(256), 0, stream,
                     x, w1b, b1, w2b, b2, gamma, beta, counts, lists, out);
}

// Round 3
// 271.566 us; speedup vs baseline: 1.1044x; 1.1044x over previous
//
#include <hip/hip_runtime.h>

#define TOK 65536
#define DM 256
#define DF 1024
#define NB 4

typedef unsigned short ushort_t;
typedef unsigned int uint32;

typedef __attribute__((ext_vector_type(8))) short bf16x8;
typedef __attribute__((ext_vector_type(4))) float f32x4;

__device__ inline ushort_t f2bf(float f) {
  union { float f; unsigned int u; } v; v.f = f;
  unsigned int u = v.u;
  unsigned int r = (u + 0x7FFFu + ((u >> 16) & 1u)) >> 16;
  return (ushort_t)r;
}
__device__ inline uint32 pack2(float a, float b) {
  return (uint32)f2bf(a) | ((uint32)f2bf(b) << 16);
}

// ---------------- kernel 0: convert w1/w2 fp32 -> bf16 + zero counts --------
// grid (1024, 2) x 256 threads; 4 floats per thread.
__global__ __launch_bounds__(256) void prep_weights_kernel(
    const float* __restrict__ w1, const float* __restrict__ w2,
    ushort_t* __restrict__ w1b, ushort_t* __restrict__ w2b,
    int* __restrict__ counts)
{
  if (blockIdx.x == 0 && blockIdx.y == 0 && threadIdx.x < NB)
    counts[threadIdx.x] = 0;
  const int idx = blockIdx.x * 256 + threadIdx.x;   // float4 index
  const float* src = blockIdx.y ? w2 : w1;
  ushort_t* dst = blockIdx.y ? w2b : w1b;
  float4 v = ((const float4*)src)[idx];
  uint2 p;
  p.x = pack2(v.x, v.y);
  p.y = pack2(v.z, v.w);
  *(uint2*)(dst + (size_t)idx * 4) = p;
}

// ---------------- kernel 1: route tokens to per-branch lists + zero-fill ----
__global__ __launch_bounds__(256) void route_kernel(
    const int* __restrict__ b_seq, int* __restrict__ counts,
    ushort_t* __restrict__ lists, uint32* __restrict__ out32)
{
  __shared__ int s_lpos[NB];
  __shared__ int s_lbase[NB];
  __shared__ int s_b[256];
  const int tid = threadIdx.x;
  const int base = blockIdx.x * 256;
  const int token = base + tid;
  if (tid < NB) s_lpos[tid] = 0;
  __syncthreads();
  const int b = b_seq[token];
  s_b[tid] = b;
  int my = 0;
  if (b > 0) my = atomicAdd(&s_lpos[b - 1], 1);
  __syncthreads();
  if (tid < NB) s_lbase[tid] = atomicAdd(&counts[tid], s_lpos[tid]);
  __syncthreads();
  if (b > 0) lists[(b - 1) * TOK + s_lbase[b - 1] + my] = (ushort_t)token;
  // zero-fill rows of inactive tokens (b==0): 256 fp32 dwords per row
  #pragma unroll 4
  for (int it = 0; it < 256; ++it) {
    int flat = it * 256 + tid;
    int tl = flat >> 8;
    int j = flat & 255;
    if (s_b[tl] == 0) out32[(size_t)(base + tl) * DM + j] = 0u;
  }
}

// ---------------- kernel 2: fused FFN + LN over gathered token tiles --------
// 1-D grid of 4096, decoded so branch n -> XCD pair {2n,2n+1} (L2 locality).
// block = 256 (4 waves). Tile: M=64 tokens. Loop D_FF in 16 chunks of F=64.
// Weight loads are register-batched per chunk; sH is double-buffered so each
// chunk has a single barrier.
__global__ __launch_bounds__(256, 2) void ffn_kernel(
    const float* __restrict__ x,
    const ushort_t* __restrict__ w1b_all, const float* __restrict__ b1,
    const ushort_t* __restrict__ w2b_all, const float* __restrict__ b2,
    const float* __restrict__ gamma, const float* __restrict__ beta,
    const int* __restrict__ counts, const ushort_t* __restrict__ lists,
    float* __restrict__ out)
{
  const int id = blockIdx.x;
  const int slot = id & 7;                 // putative XCD
  const int n = slot >> 1;                 // branch -> XCD pair
  const int tile = ((id >> 3) << 1) + (slot & 1);
  const int cnt = counts[n];
  const int tile0 = tile * 64;
  if (tile0 >= cnt) return;
  const int mvalid = min(64, cnt - tile0);

  __shared__ int s_idx[64];
  __shared__ __align__(16) ushort_t sX[64][264];     // 256 + 8 pad
  __shared__ __align__(16) ushort_t sH[2][64][72];   // double-buffered
  __shared__ float s_ps[4][64];
  __shared__ float s_pq[4][64];
  __shared__ float s_mu[64];
  __shared__ float s_rs[64];

  const int tid  = threadIdx.x;
  const int wave = tid >> 6;
  const int lane = tid & 63;
  const int q    = lane >> 4;   // quad 0..3
  const int lc   = lane & 15;   // intra-tile row/col index

  if (tid < 64) {
    int i = tile0 + tid;
    s_idx[tid] = (int)lists[n * TOK + (i < cnt ? i : tile0)];
  }
  __syncthreads();

  // stage X tile: 64 rows x 256 fp32 -> bf16 in LDS
  #pragma unroll
  for (int it = 0; it < 16; ++it) {
    int chunk = it * 256 + tid;
    int r = chunk >> 6;
    int c = (chunk & 63) << 2;
    float4 v = *(const float4*)(x + (size_t)s_idx[r] * DM + c);
    uint2 p;
    p.x = pack2(v.x, v.y);
    p.y = pack2(v.z, v.w);
    *(uint2*)(&sX[r][c]) = p;
  }
  __syncthreads();

  f32x4 yacc[4][4];
  #pragma unroll
  for (int mi = 0; mi < 4; ++mi)
    #pragma unroll
    for (int di = 0; di < 4; ++di)
      yacc[mi][di] = (f32x4){0.f, 0.f, 0.f, 0.f};

  const ushort_t* w1b = w1b_all + (size_t)n * DF * DM;
  const ushort_t* w2b = w2b_all + (size_t)n * DM * DF;

  // preload GEMM1 weight frags for chunk 0
  bf16x8 wb1[2][8];
  {
    const ushort_t* w1row0 = w1b + (size_t)(wave * 16 + lc) * DM;
    #pragma unroll
    for (int ks = 0; ks < 8; ++ks)
      wb1[0][ks] = *(const bf16x8*)(w1row0 + ks * 32 + q * 8);
  }

  #pragma unroll 2
  for (int fc = 0; fc < 16; ++fc) {
    const int p = fc & 1;
    const int f0 = fc * 64;
    const int fcol = f0 + wave * 16 + lc;

    // ---- batched loads: GEMM2 frags for THIS chunk (drained at barrier)
    bf16x8 wb2[8];
    #pragma unroll
    for (int ks = 0; ks < 2; ++ks)
      #pragma unroll
      for (int di = 0; di < 4; ++di)
        wb2[ks * 4 + di] = *(const bf16x8*)(
            w2b + (size_t)(wave * 64 + di * 16 + lc) * DF + f0 + ks * 32 + q * 8);
    // ---- batched loads: GEMM1 frags for NEXT chunk (consumed next iter)
    {
      const int fcn = (fc < 15) ? (fc + 1) : 15;
      const ushort_t* w1rown = w1b + (size_t)(fcn * 64 + wave * 16 + lc) * DM;
      #pragma unroll
      for (int ks = 0; ks < 8; ++ks)
        wb1[p ^ 1][ks] = *(const bf16x8*)(w1rown + ks * 32 + q * 8);
    }

    // ---- GEMM1: H[64 x 64] over K=256, from resident regs wb1[p]
    f32x4 hacc[4];
    #pragma unroll
    for (int mi = 0; mi < 4; ++mi) hacc[mi] = (f32x4){0.f, 0.f, 0.f, 0.f};
    #pragma unroll
    for (int ks = 0; ks < 8; ++ks) {
      #pragma unroll
      for (int mi = 0; mi < 4; ++mi) {
        bf16x8 afrag = *(const bf16x8*)(&sX[mi * 16 + lc][ks * 32 + q * 8]);
        hacc[mi] = __builtin_amdgcn_mfma_f32_16x16x32_bf16(afrag, wb1[p][ks], hacc[mi], 0, 0, 0);
      }
    }
    const float b1v = b1[n * DF + fcol];
    // ---- ELU + bias, C-layout -> row-major bf16 in LDS buffer p
    #pragma unroll
    for (int mi = 0; mi < 4; ++mi) {
      #pragma unroll
      for (int r = 0; r < 4; ++r) {
        float v = hacc[mi][r] + b1v;
        v = (v > 0.f) ? v : (__expf(v) - 1.f);
        sH[p][mi * 16 + q * 4 + r][wave * 16 + lc] = f2bf(v);
      }
    }
    __syncthreads();   // single barrier: sH[p] ready; wb2 drained too
    // ---- GEMM2: Y[64 x 256] += H @ W2^T from regs wb2 + sH[p]
    #pragma unroll
    for (int ks = 0; ks < 2; ++ks) {
      bf16x8 af[4];
      #pragma unroll
      for (int mi = 0; mi < 4; ++mi)
        af[mi] = *(const bf16x8*)(&sH[p][mi * 16 + lc][ks * 32 + q * 8]);
      #pragma unroll
      for (int di = 0; di < 4; ++di)
        #pragma unroll
        for (int mi = 0; mi < 4; ++mi)
          yacc[mi][di] = __builtin_amdgcn_mfma_f32_16x16x32_bf16(af[mi], wb2[ks * 4 + di], yacc[mi][di], 0, 0, 0);
    }
  }

  // ---- epilogue: +b2, LayerNorm stats (cross-wave), gamma/beta, scatter out
  float b2v[4], gv[4], bv[4];
  #pragma unroll
  for (int di = 0; di < 4; ++di) {
    int dcol = wave * 64 + di * 16 + lc;
    b2v[di] = b2[n * DM + dcol];
    gv[di]  = gamma[n * DM + dcol];
    bv[di]  = beta[n * DM + dcol];
  }
  #pragma unroll
  for (int mi = 0; mi < 4; ++mi)
    #pragma unroll
    for (int di = 0; di < 4; ++di)
      #pragma unroll
      for (int r = 0; r < 4; ++r)
        yacc[mi][di][r] += b2v[di];

  #pragma unroll
  for (int mi = 0; mi < 4; ++mi) {
    #pragma unroll
    for (int r = 0; r < 4; ++r) {
      float s = 0.f, sq = 0.f;
      #pragma unroll
      for (int di = 0; di < 4; ++di) {
        float v = yacc[mi][di][r];
        s += v; sq += v * v;
      }
      #pragma unroll
      for (int off = 1; off < 16; off <<= 1) {
        s  += __shfl_xor(s, off, 64);
        sq += __shfl_xor(sq, off, 64);
      }
      if (lc == 0) {
        int m = mi * 16 + q * 4 + r;
        s_ps[wave][m] = s;
        s_pq[wave][m] = sq;
      }
    }
  }
  __syncthreads();
  if (tid < 64) {
    float s  = s_ps[0][tid] + s_ps[1][tid] + s_ps[2][tid] + s_ps[3][tid];
    float sq = s_pq[0][tid] + s_pq[1][tid] + s_pq[2][tid] + s_pq[3][tid];
    float mu = s * (1.f / 256.f);
    float var = fmaxf(sq * (1.f / 256.f) - mu * mu, 0.f);
    s_mu[tid] = mu;
    s_rs[tid] = rsqrtf(var + 1e-12f);
  }
  __syncthreads();

  #pragma unroll
  for (int mi = 0; mi < 4; ++mi) {
    #pragma unroll
    for (int r = 0; r < 4; ++r) {
      int m = mi * 16 + q * 4 + r;
      if (m < mvalid) {
        float mu = s_mu[m], rs = s_rs[m];
        size_t rowbase = (size_t)s_idx[m] * DM;
        #pragma unroll
        for (int di = 0; di < 4; ++di) {
          int dcol = wave * 64 + di * 16 + lc;
          float v = (yacc[mi][di][r] - mu) * rs * gv[di] + bv[di];
          out[rowbase + dcol] = v;
        }
      }
    }
  }
}

extern "C" void kernel_launch(void* const* d_in, const int* in_sizes, int n_in,
                              void* d_out, int out_size, void* d_ws, size_t ws_size,
                              hipStream_t stream) {
  const float* x     = (const float*)d_in[0];
  const int*   b_seq = (const int*)d_in[1];
  const float* w1    = (const float*)d_in[2];
  const float* b1    = (const float*)d_in[3];
  const float* w2    = (const float*)d_in[4];
  const float* b2    = (const float*)d_in[5];
  const float* gamma = (const float*)d_in[6];
  const float* beta  = (const float*)d_in[7];
  float* out = (float*)d_out;

  int* counts = (int*)d_ws;
  ushort_t* lists = (ushort_t*)((char*)d_ws + 256);                 // 512 KB
  ushort_t* w1b = (ushort_t*)((char*)d_ws + 256 + 512 * 1024);      // 2 MB
  ushort_t* w2b = w1b + (size_t)NB * DF * DM;                       // 2 MB

  hipLaunchKernelGGL(prep_weights_kernel, dim3(1024, 2), dim3(256), 0, stream,
                     w1, w2, w1b, w2b, counts);
  hipLaunchKernelGGL(route_kernel, dim3(TOK / 256), dim3(256), 0, stream,
                     b_seq, counts, lists, (uint32*)d_out);
  hipLaunchKernelGGL(ffn_kernel, dim3(4096), dim3(256), 0, stream,
                     x, w1b, b1, w2b, b2, gamma, beta, counts, lists, out);
}